// Round 9
// baseline (345.239 us; speedup 1.0000x reference)
//
#include <hip/hip_runtime.h>
#include <hip/hip_bf16.h>

// RetrieverBase: q[64][32][128] f32, p[128][180][128] f32
// out = concat(term_relevance[64][128][32][180], query_maxsim[64][128][32], relevance[64][128])
#define A_N 64
#define B_N 128
#define Q_N 32
#define D_N 180
#define V_N 128

typedef __attribute__((ext_vector_type(8))) short bf16x8;   // 8 bf16 (4 VGPRs)
typedef __attribute__((ext_vector_type(4))) float f32x4;

__device__ __forceinline__ short f2bf(float f) {
  __hip_bfloat16 h = __float2bfloat16(f);
  return (short)__builtin_bit_cast(unsigned short, h);
}

__device__ __forceinline__ bf16x8 pack8(const f32x4& lo, const f32x4& hi) {
  bf16x8 v;
  v[0] = f2bf(lo[0]); v[1] = f2bf(lo[1]); v[2] = f2bf(lo[2]); v[3] = f2bf(lo[3]);
  v[4] = f2bf(hi[0]); v[5] = f2bf(hi[1]); v[6] = f2bf(hi[2]); v[7] = f2bf(hi[3]);
  return v;
}

// R7 (67.5us) refined for exact residency:
//   grid 512 = 4 a-slots x 128 b (b FAST: bid%8==b%8 -> each XCD's 16
//   p-passages stay L2-resident). Block = 512 thr = 8 waves, ONE b.
//   2 blocks/CU EXACTLY (92KB LDS, 16 waves/CU), one block round, and each
//   wave runs TWO independent (a,b) jobs -> p staged ONCE per block (R7
//   staged it twice as many times) and stores flow continuously wave-private.
// Structure per job (identical to R7): p fragments from XOR-swizzled LDS
// (conflict-free ds_read_b128), q from L2, stores straight from MFMA accs
// (same wave completes straddled lines ~150cy apart -> L2 merges), reductions
// in-register, ZERO barriers after the single staging __syncthreads.
__global__ __launch_bounds__(512, 4) void score_kernel(
    const float* __restrict__ q, const float* __restrict__ p,
    float* __restrict__ out) {
  const int bid  = blockIdx.x;
  const int b    = bid & (B_N - 1);
  const int aslot = bid >> 7;         // 0..3 -> a = aslot*16 + j*8 + wv
  const int tid  = threadIdx.x;
  const int wv   = tid >> 6;          // 0..7
  const int lane = tid & 63;
  const int l16  = lane & 15;
  const int g    = lane >> 4;         // 0..3

  const float* __restrict__ pb = p + (size_t)b * D_N * V_N;

  // ---- stage p[b] -> LDS bf16, swizzled: 2880 16B-chunks over 512 threads ----
  __shared__ ushort plds[D_N * V_N];   // 46080 B
  for (int c = tid; c < D_N * (V_N / 8); c += 512) {
    const int r  = c >> 4;
    const int s  = c & 15;
    const int sp = (s & 8) | ((s & 7) ^ (r & 7));
    const float* src = pb + (size_t)r * V_N + s * 8;
    *reinterpret_cast<bf16x8*>(&plds[r * V_N + sp * 8]) =
        pack8(*reinterpret_cast<const f32x4*>(src),
              *reinterpret_cast<const f32x4*>(src + 4));
  }
  __syncthreads();   // staging complete — the ONLY barrier

  const size_t TERM_SZ = (size_t)A_N * B_N * Q_N * D_N;

#pragma unroll 1
  for (int j = 0; j < 2; ++j) {
    const int a = aslot * 16 + j * 8 + wv;

    // q as B-fragments: B[k][col=q]; lane reads q[qt*16+l16][kk*32+g*8 ..+7]
    const float* __restrict__ qa = q + (size_t)a * Q_N * V_N;
    bf16x8 qf[2][4];
#pragma unroll
    for (int qt = 0; qt < 2; ++qt)
#pragma unroll
      for (int kk = 0; kk < 4; ++kk) {
        const float* s = qa + (size_t)(qt * 16 + l16) * V_N + kk * 32 + g * 8;
        qf[qt][kk] = pack8(*reinterpret_cast<const f32x4*>(s),
                           *reinterpret_cast<const f32x4*>(s + 4));
      }

    float qm0 = -INFINITY, qm1 = -INFINITY;
    const size_t outbase = ((size_t)a * B_N + b) * (size_t)(Q_N * D_N);

#pragma unroll
    for (int dt = 0; dt < 12; ++dt) {
      const int drow = dt * 16 + l16;
      const int dr   = drow < D_N ? drow : (D_N - 1);  // tail clamp, max-safe

      // A-fragments from LDS: p-row dr, k-chunk slot kk*4+g (swizzled)
      bf16x8 pf[4];
#pragma unroll
      for (int kk = 0; kk < 4; ++kk) {
        const int s  = kk * 4 + g;
        const int sp = (s & 8) | ((s & 7) ^ (dr & 7));
        pf[kk] = *reinterpret_cast<const bf16x8*>(&plds[dr * V_N + sp * 8]);
      }

      f32x4 acc0 = (f32x4){0.f, 0.f, 0.f, 0.f};
      f32x4 acc1 = (f32x4){0.f, 0.f, 0.f, 0.f};
#pragma unroll
      for (int kk = 0; kk < 4; ++kk) {
        acc0 = __builtin_amdgcn_mfma_f32_16x16x32_bf16(pf[kk], qf[0][kk], acc0, 0, 0, 0);
        acc1 = __builtin_amdgcn_mfma_f32_16x16x32_bf16(pf[kk], qf[1][kk], acc1, 0, 0, 0);
      }

      // C/D layout: col=l16=q, row=g*4+reg=d-in-tile; dt==11,g>0 masked (dups)
      qm0 = fmaxf(qm0, fmaxf(fmaxf(acc0[0], acc0[1]), fmaxf(acc0[2], acc0[3])));
      qm1 = fmaxf(qm1, fmaxf(fmaxf(acc1[0], acc1[1]), fmaxf(acc1[2], acc1[3])));
      const int d0 = dt * 16 + g * 4;
      if (d0 < D_N) {
        *reinterpret_cast<f32x4*>(out + outbase + (size_t)l16 * D_N + d0)        = acc0;
        *reinterpret_cast<f32x4*>(out + outbase + (size_t)(16 + l16) * D_N + d0) = acc1;
      }
    }

    // max across the 4 g-groups (different d sub-rows, same q)
    qm0 = fmaxf(qm0, __shfl_xor(qm0, 16, 64));
    qm0 = fmaxf(qm0, __shfl_xor(qm0, 32, 64));
    qm1 = fmaxf(qm1, __shfl_xor(qm1, 16, 64));
    qm1 = fmaxf(qm1, __shfl_xor(qm1, 32, 64));

    if (lane < 16) {   // maxsim for q = qt*16 + lane
      float* ms = out + TERM_SZ + ((size_t)a * B_N + b) * Q_N;
      ms[lane]      = qm0;
      ms[16 + lane] = qm1;
    }

    // relevance = sum over 32 q of maxsim (qm replicated across g-groups)
    float s = qm0 + qm1;
    s += __shfl_xor(s, 1, 64);
    s += __shfl_xor(s, 2, 64);
    s += __shfl_xor(s, 4, 64);
    s += __shfl_xor(s, 8, 64);
    if (lane == 0)
      out[TERM_SZ + (size_t)A_N * B_N * Q_N + (size_t)a * B_N + b] = s;
  }
}

extern "C" void kernel_launch(void* const* d_in, const int* in_sizes, int n_in,
                              void* d_out, int out_size, void* d_ws, size_t ws_size,
                              hipStream_t stream) {
  const float* q = (const float*)d_in[0];
  const float* p = (const float*)d_in[1];
  float* out = (float*)d_out;
  dim3 grid(512);    // 4 a-slots x 128 b (b fast -> XCD-stable p residency)
  dim3 block(512);   // 8 waves; stage p[b] once, then 2 jobs per wave
  hipLaunchKernelGGL(score_kernel, grid, block, 0, stream, q, p, out);
}

// Round 11
// 63.874 us; speedup vs baseline: 5.4050x; 5.4050x over previous
//
#include <hip/hip_runtime.h>
#include <hip/hip_bf16.h>

// RetrieverBase: q[64][32][128] f32, p[128][180][128] f32
// out = concat(term_relevance[64][128][32][180], query_maxsim[64][128][32], relevance[64][128])
#define A_N 64
#define B_N 128
#define Q_N 32
#define D_N 180
#define V_N 128

typedef __attribute__((ext_vector_type(8))) short bf16x8;   // 8 bf16 (4 VGPRs)
typedef __attribute__((ext_vector_type(4))) float f32x4;

__device__ __forceinline__ short f2bf(float f) {
  __hip_bfloat16 h = __float2bfloat16(f);
  return (short)__builtin_bit_cast(unsigned short, h);
}

__device__ __forceinline__ bf16x8 pack8(const f32x4& lo, const f32x4& hi) {
  bf16x8 v;
  v[0] = f2bf(lo[0]); v[1] = f2bf(lo[1]); v[2] = f2bf(lo[2]); v[3] = f2bf(lo[3]);
  v[4] = f2bf(hi[0]); v[5] = f2bf(hi[1]); v[6] = f2bf(hi[2]); v[7] = f2bf(hi[3]);
  return v;
}

// Per-wave LDS fence: drain this wave's DS queue (cross-lane write->read
// visibility) and pin compiler scheduling (guide rule #18). NOT a block
// barrier -- other waves keep flowing.
__device__ __forceinline__ void lds_fence() {
  asm volatile("s_waitcnt lgkmcnt(0)" ::: "memory");
  __builtin_amdgcn_sched_barrier(0);
}

// R7 champion (67.5us) + per-wave LDS store-combining, R10 bug fixed.
// R10 failed with stale-data symptoms: the combine's ds_write -> ds_read
// handoff is CROSS-LANE within the wave, so the compiler sees no per-thread
// dependency and nothing forced lgkmcnt drain / scheduling order. Fix:
// explicit lds_fence() between phases (write->read and read->reuse).
//
// Kept from R7 (empirical rules R4/R9: one job per wave, grid >= 1024):
// grid 1024 = 8 ag x 128 b (b fast: bid%8==b%8 pins each XCD's 16 p-passages
// in its L2), block 512 = 8 waves, p[b] staged once to swizzled LDS, zero
// block barriers after staging, in-register reductions.
// New: per 4-dt group and q-half, wave round-trips accs through a PRIVATE
// 4KB LDS tile and stores 4-rows x 256B contiguous spans (19 line-txns/KB
// vs 28 direct 16B@720B-stride) -- attacks the store-request bound
// (fill kernel proves 6.8 TB/s with full-line writes; R7 got 3.5).
__global__ __launch_bounds__(512, 4) void score_kernel(
    const float* __restrict__ q, const float* __restrict__ p,
    float* __restrict__ out) {
  const int bid  = blockIdx.x;
  const int b    = bid & (B_N - 1);
  const int ag   = bid >> 7;          // 0..7
  const int tid  = threadIdx.x;
  const int wv   = tid >> 6;          // 0..7
  const int lane = tid & 63;
  const int l16  = lane & 15;
  const int g    = lane >> 4;         // 0..3
  const int a    = ag * 8 + wv;       // ONE job per wave

  const float* __restrict__ pb = p + (size_t)b * D_N * V_N;

  // ---- stage p[b] -> LDS bf16, swizzled: 2880 16B-chunks over 512 threads ----
  __shared__ ushort plds[D_N * V_N];                 // 46080 B
  __shared__ __align__(16) float cbuf[8][1024];      // 8 x 4KB wave-private tiles
  for (int c = tid; c < D_N * (V_N / 8); c += 512) {
    const int r  = c >> 4;
    const int s  = c & 15;
    const int sp = (s & 8) | ((s & 7) ^ (r & 7));
    const float* src = pb + (size_t)r * V_N + s * 8;
    *reinterpret_cast<bf16x8*>(&plds[r * V_N + sp * 8]) =
        pack8(*reinterpret_cast<const f32x4*>(src),
              *reinterpret_cast<const f32x4*>(src + 4));
  }

  // q as B-fragments: B[k][col=q]; lane reads q[qt*16+l16][kk*32+g*8 ..+7]
  const float* __restrict__ qa = q + (size_t)a * Q_N * V_N;
  bf16x8 qf[2][4];
#pragma unroll
  for (int qt = 0; qt < 2; ++qt)
#pragma unroll
    for (int kk = 0; kk < 4; ++kk) {
      const float* s = qa + (size_t)(qt * 16 + l16) * V_N + kk * 32 + g * 8;
      qf[qt][kk] = pack8(*reinterpret_cast<const f32x4*>(s),
                         *reinterpret_cast<const f32x4*>(s + 4));
    }

  __syncthreads();   // staging complete — the ONLY block barrier

  float* cw = cbuf[wv];
  float qm0 = -INFINITY, qm1 = -INFINITY;
  const size_t outbase = ((size_t)a * B_N + b) * (size_t)(Q_N * D_N);

#pragma unroll
  for (int dtg = 0; dtg < 3; ++dtg) {     // 3 groups of 4 d-tiles (64 d each)
    const int nvalid = (dtg < 2) ? 16 : 13;   // last group: d 128..179 = 13 chunks
#pragma unroll
    for (int qt = 0; qt < 2; ++qt) {      // split q-halves: acc live = 16 VGPR
      f32x4 acc[4];

#pragma unroll
      for (int t = 0; t < 4; ++t) {
        const int dt   = dtg * 4 + t;
        const int drow = dt * 16 + l16;
        const int dr   = drow < D_N ? drow : (D_N - 1);  // tail clamp, max-safe

        // A-fragments from LDS: p-row dr, k-chunk slot kk*4+g (swizzled)
        bf16x8 pf[4];
#pragma unroll
        for (int kk = 0; kk < 4; ++kk) {
          const int s  = kk * 4 + g;
          const int sp = (s & 8) | ((s & 7) ^ (dr & 7));
          pf[kk] = *reinterpret_cast<const bf16x8*>(&plds[dr * V_N + sp * 8]);
        }

        acc[t] = (f32x4){0.f, 0.f, 0.f, 0.f};
#pragma unroll
        for (int kk = 0; kk < 4; ++kk)
          acc[t] = __builtin_amdgcn_mfma_f32_16x16x32_bf16(pf[kk], qf[qt][kk], acc[t], 0, 0, 0);

        const float m = fmaxf(fmaxf(acc[t][0], acc[t][1]), fmaxf(acc[t][2], acc[t][3]));
        if (qt == 0) qm0 = fmaxf(qm0, m); else qm1 = fmaxf(qm1, m);
      }

      // ---- combine write: lane (l16,g) holds chunk c16=t*4+g of row l16 ----
      // (C/D layout: col=l16=q-row of tile, row=g*4+reg = d offset -> chunk)
#pragma unroll
      for (int t = 0; t < 4; ++t) {
        const int c16 = t * 4 + g;
        const int ph  = (l16 << 4) | (c16 & 8) | ((c16 & 7) ^ (l16 & 7));
        *reinterpret_cast<f32x4*>(&cw[ph * 4]) = acc[t];
      }
      lds_fence();   // cross-lane: writes must complete before transposed reads

      // ---- transposed read + store: instr k = rows k*4..k*4+3 x 256B spans,
      // lane-ascending -> ~19 line-txns per KB (vs 28 direct) ----
#pragma unroll
      for (int k = 0; k < 4; ++k) {
        const int row = k * 4 + g;
        const int c16 = l16;
        const int ph  = (row << 4) | (c16 & 8) | ((c16 & 7) ^ (row & 7));
        f32x4 v = *reinterpret_cast<const f32x4*>(&cw[ph * 4]);
        if (c16 < nvalid)
          *reinterpret_cast<f32x4*>(out + outbase +
              (size_t)(qt * 16 + row) * D_N + dtg * 64 + c16 * 4) = v;
      }
      lds_fence();   // WAR: reads landed in VGPRs before slots are rewritten
    }
  }

  // max across the 4 g-groups (different d sub-rows, same q)
  qm0 = fmaxf(qm0, __shfl_xor(qm0, 16, 64));
  qm0 = fmaxf(qm0, __shfl_xor(qm0, 32, 64));
  qm1 = fmaxf(qm1, __shfl_xor(qm1, 16, 64));
  qm1 = fmaxf(qm1, __shfl_xor(qm1, 32, 64));

  const size_t TERM_SZ = (size_t)A_N * B_N * Q_N * D_N;
  if (lane < 16) {   // maxsim for q = qt*16 + lane
    float* ms = out + TERM_SZ + ((size_t)a * B_N + b) * Q_N;
    ms[lane]      = qm0;
    ms[16 + lane] = qm1;
  }

  // relevance = sum over 32 q of maxsim (qm replicated across g-groups)
  float s = qm0 + qm1;
  s += __shfl_xor(s, 1, 64);
  s += __shfl_xor(s, 2, 64);
  s += __shfl_xor(s, 4, 64);
  s += __shfl_xor(s, 8, 64);
  if (lane == 0)
    out[TERM_SZ + (size_t)A_N * B_N * Q_N + (size_t)a * B_N + b] = s;
}

extern "C" void kernel_launch(void* const* d_in, const int* in_sizes, int n_in,
                              void* d_out, int out_size, void* d_ws, size_t ws_size,
                              hipStream_t stream) {
  const float* q = (const float*)d_in[0];
  const float* p = (const float*)d_in[1];
  float* out = (float*)d_out;
  dim3 grid(1024);   // 8 a-groups x 128 b (b fast -> XCD-stable p residency)
  dim3 block(512);   // 8 waves; one (a,b) job per wave
  hipLaunchKernelGGL(score_kernel, grid, block, 0, stream, q, p, out);
}

// Round 12
// 55.974 us; speedup vs baseline: 6.1678x; 1.1411x over previous
//
#include <hip/hip_runtime.h>
#include <hip/hip_bf16.h>

// RetrieverBase: q[64][32][128] f32, p[128][180][128] f32
// out = concat(term_relevance[64][128][32][180], query_maxsim[64][128][32], relevance[64][128])
#define A_N 64
#define B_N 128
#define Q_N 32
#define D_N 180
#define V_N 128

typedef __attribute__((ext_vector_type(8))) short bf16x8;   // 8 bf16 (4 VGPRs)
typedef __attribute__((ext_vector_type(4))) float f32x4;

__device__ __forceinline__ short f2bf(float f) {
  __hip_bfloat16 h = __float2bfloat16(f);
  return (short)__builtin_bit_cast(unsigned short, h);
}

__device__ __forceinline__ bf16x8 pack8(const f32x4& lo, const f32x4& hi) {
  bf16x8 v;
  v[0] = f2bf(lo[0]); v[1] = f2bf(lo[1]); v[2] = f2bf(lo[2]); v[3] = f2bf(lo[3]);
  v[4] = f2bf(hi[0]); v[5] = f2bf(hi[1]); v[6] = f2bf(hi[2]); v[7] = f2bf(hi[3]);
  return v;
}

// Per-wave LDS fence (R11-proven): drain this wave's DS queue for the
// cross-lane ds_write -> ds_read handoff; NOT a block barrier.
__device__ __forceinline__ void lds_fence() {
  asm volatile("s_waitcnt lgkmcnt(0)" ::: "memory");
  __builtin_amdgcn_sched_barrier(0);
}

// R11 (63.9us) taken to the store-pattern endpoint + LDS-traffic cut:
//  - wave holds ALL 24 accs (acc[2][12], 96 VGPR; LDS caps us at 1 block/CU
//    anyway so VGPR is free), pf read ONCE per dt (48 DS instrs vs R11's 96)
//  - per q-half: write 16 complete 720B rows into an 11.5KB wave-private
//    cbuf (packed, 16B-aligned, 2-way banks = free), then stream it out
//    LINEARLY: 11.25KB contiguous 64B-aligned = 180 FULL lines, 0 partials
//    (byte-identical pattern to the harness fill kernel's 6.9 TB/s)
//  - DS instrs/job 144 -> 84, fences 12 -> 4
// Kept (empirical rules R4/R9: one job/wave, grid >= 1024; R5/R8: no block
// barriers in hot path): grid 1024 = 8 ag x 128 b (b fast: bid%8==b%8 pins
// each XCD's 16 p-passages in L2), block 512 = 8 waves, p[b] staged once to
// swizzled LDS, in-register maxsim/relevance.
// LDS: plds 46080 + cbuf 8x11520 = 138240 B -> 1 block/CU (8 waves). This
// trades occupancy for the perfect write pattern -- the round's experiment.
__global__ __launch_bounds__(512, 2) void score_kernel(
    const float* __restrict__ q, const float* __restrict__ p,
    float* __restrict__ out) {
  const int bid  = blockIdx.x;
  const int b    = bid & (B_N - 1);
  const int ag   = bid >> 7;          // 0..7
  const int tid  = threadIdx.x;
  const int wv   = tid >> 6;          // 0..7
  const int lane = tid & 63;
  const int l16  = lane & 15;
  const int g    = lane >> 4;         // 0..3
  const int a    = ag * 8 + wv;       // ONE job per wave

  const float* __restrict__ pb = p + (size_t)b * D_N * V_N;

  // ---- stage p[b] -> LDS bf16, swizzled: 2880 16B-chunks over 512 threads ----
  __shared__ ushort plds[D_N * V_N];                    // 46080 B
  __shared__ __align__(16) float cbuf[8][16 * D_N];     // 8 x 11520 B
  for (int c = tid; c < D_N * (V_N / 8); c += 512) {
    const int r  = c >> 4;
    const int s  = c & 15;
    const int sp = (s & 8) | ((s & 7) ^ (r & 7));
    const float* src = pb + (size_t)r * V_N + s * 8;
    *reinterpret_cast<bf16x8*>(&plds[r * V_N + sp * 8]) =
        pack8(*reinterpret_cast<const f32x4*>(src),
              *reinterpret_cast<const f32x4*>(src + 4));
  }

  // q as B-fragments: B[k][col=q]; lane reads q[qt*16+l16][kk*32+g*8 ..+7]
  const float* __restrict__ qa = q + (size_t)a * Q_N * V_N;
  bf16x8 qf[2][4];
#pragma unroll
  for (int qt = 0; qt < 2; ++qt)
#pragma unroll
    for (int kk = 0; kk < 4; ++kk) {
      const float* s = qa + (size_t)(qt * 16 + l16) * V_N + kk * 32 + g * 8;
      qf[qt][kk] = pack8(*reinterpret_cast<const f32x4*>(s),
                         *reinterpret_cast<const f32x4*>(s + 4));
    }

  __syncthreads();   // staging complete — the ONLY block barrier

  // ---- compute: all 12 d-tiles, both q-halves; pf read once per dt ----
  f32x4 acc[2][12];
#pragma unroll
  for (int qt = 0; qt < 2; ++qt)
#pragma unroll
    for (int dt = 0; dt < 12; ++dt)
      acc[qt][dt] = (f32x4){0.f, 0.f, 0.f, 0.f};

#pragma unroll
  for (int dt = 0; dt < 12; ++dt) {
    const int drow = dt * 16 + l16;
    const int dr   = drow < D_N ? drow : (D_N - 1);  // tail clamp, max-safe

    bf16x8 pf[4];
#pragma unroll
    for (int kk = 0; kk < 4; ++kk) {
      const int s  = kk * 4 + g;
      const int sp = (s & 8) | ((s & 7) ^ (dr & 7));
      pf[kk] = *reinterpret_cast<const bf16x8*>(&plds[dr * V_N + sp * 8]);
    }
#pragma unroll
    for (int kk = 0; kk < 4; ++kk) {
      acc[0][dt] = __builtin_amdgcn_mfma_f32_16x16x32_bf16(pf[kk], qf[0][kk], acc[0][dt], 0, 0, 0);
      acc[1][dt] = __builtin_amdgcn_mfma_f32_16x16x32_bf16(pf[kk], qf[1][kk], acc[1][dt], 0, 0, 0);
    }
  }

  // per-lane maxsim over all owned d (clamped dups are max-safe)
  float qm[2] = {-INFINITY, -INFINITY};
#pragma unroll
  for (int qt = 0; qt < 2; ++qt)
#pragma unroll
    for (int dt = 0; dt < 12; ++dt)
      qm[qt] = fmaxf(qm[qt], fmaxf(fmaxf(acc[qt][dt][0], acc[qt][dt][1]),
                                   fmaxf(acc[qt][dt][2], acc[qt][dt][3])));

  // ---- store: per q-half, assemble 16 full rows in cbuf, stream linearly ----
  // C/D layout: col=l16=q-row, row=g*4+reg = d offset within tile.
  // cbuf write: byte = l16*720 + dt*64 + g*16 (16B-aligned; banks 2-way=free)
  // linear read+store: lane-ascending 16B, 11.25KB contiguous 64B-aligned
  // region = 180 full lines, zero partials (fill-kernel pattern).
  float* cw = cbuf[wv];
  const size_t outb = ((size_t)a * B_N + b) * (size_t)(Q_N * D_N);

#pragma unroll
  for (int qt = 0; qt < 2; ++qt) {
#pragma unroll
    for (int dt = 0; dt < 12; ++dt) {
      if (dt < 11 || g == 0)   // dt==11: only d 176..179 (g==0) valid
        *reinterpret_cast<f32x4*>(&cw[l16 * D_N + dt * 16 + g * 4]) = acc[qt][dt];
    }
    lds_fence();   // cross-lane: row writes visible before linear reads

#pragma unroll
    for (int c = 0; c < 12; ++c) {       // 11 x 1KB + 1 x 256B (lanes<16)
      const int off = c * 256 + lane * 4;
      if (c < 11 || lane < 16) {
        f32x4 v = *reinterpret_cast<const f32x4*>(&cw[off]);
        *reinterpret_cast<f32x4*>(out + outb + (size_t)qt * 16 * D_N + off) = v;
      }
    }
    lds_fence();   // WAR: reads landed before qt=1 rewrites cbuf
  }

  // max across the 4 g-groups (different d sub-rows, same q)
  float qm0 = qm[0], qm1 = qm[1];
  qm0 = fmaxf(qm0, __shfl_xor(qm0, 16, 64));
  qm0 = fmaxf(qm0, __shfl_xor(qm0, 32, 64));
  qm1 = fmaxf(qm1, __shfl_xor(qm1, 16, 64));
  qm1 = fmaxf(qm1, __shfl_xor(qm1, 32, 64));

  const size_t TERM_SZ = (size_t)A_N * B_N * Q_N * D_N;
  if (lane < 16) {   // maxsim for q = qt*16 + lane
    float* ms = out + TERM_SZ + ((size_t)a * B_N + b) * Q_N;
    ms[lane]      = qm0;
    ms[16 + lane] = qm1;
  }

  // relevance = sum over 32 q of maxsim (qm replicated across g-groups)
  float s = qm0 + qm1;
  s += __shfl_xor(s, 1, 64);
  s += __shfl_xor(s, 2, 64);
  s += __shfl_xor(s, 4, 64);
  s += __shfl_xor(s, 8, 64);
  if (lane == 0)
    out[TERM_SZ + (size_t)A_N * B_N * Q_N + (size_t)a * B_N + b] = s;
}

extern "C" void kernel_launch(void* const* d_in, const int* in_sizes, int n_in,
                              void* d_out, int out_size, void* d_ws, size_t ws_size,
                              hipStream_t stream) {
  const float* q = (const float*)d_in[0];
  const float* p = (const float*)d_in[1];
  float* out = (float*)d_out;
  dim3 grid(1024);   // 8 a-groups x 128 b (b fast -> XCD-stable p residency)
  dim3 block(512);   // 8 waves; one (a,b) job per wave
  hipLaunchKernelGGL(score_kernel, grid, block, 0, stream, q, p, out);
}

// Round 13
// 53.710 us; speedup vs baseline: 6.4278x; 1.0421x over previous
//
#include <hip/hip_runtime.h>
#include <hip/hip_bf16.h>

// RetrieverBase: q[64][32][128] f32, p[128][180][128] f32
// out = concat(term_relevance[64][128][32][180], query_maxsim[64][128][32], relevance[64][128])
#define A_N 64
#define B_N 128
#define Q_N 32
#define D_N 180
#define V_N 128

typedef __attribute__((ext_vector_type(8))) short bf16x8;   // 8 bf16 (4 VGPRs)
typedef __attribute__((ext_vector_type(4))) float f32x4;

__device__ __forceinline__ short f2bf(float f) {
  __hip_bfloat16 h = __float2bfloat16(f);
  return (short)__builtin_bit_cast(unsigned short, h);
}

__device__ __forceinline__ bf16x8 pack8(const f32x4& lo, const f32x4& hi) {
  bf16x8 v;
  v[0] = f2bf(lo[0]); v[1] = f2bf(lo[1]); v[2] = f2bf(lo[2]); v[3] = f2bf(lo[3]);
  v[4] = f2bf(hi[0]); v[5] = f2bf(hi[1]); v[6] = f2bf(hi[2]); v[7] = f2bf(hi[3]);
  return v;
}

// Per-wave LDS fence (R11/R12-proven): drains this wave's DS queue for the
// cross-lane ds_write -> ds_read handoff. lgkm-only: global stores keep
// draining in the background. NOT a block barrier.
__device__ __forceinline__ void lds_fence() {
  asm volatile("s_waitcnt lgkmcnt(0)" ::: "memory");
  __builtin_amdgcn_sched_barrier(0);
}

// R12 (56.0us) + two PIPELINED jobs per wave. R12's phases were serial per
// round (stage 2us + compute 4us + store-drain 7us); with full-line cbuf
// stores the R4/R9 partial-line write-amp mechanism is impossible by
// construction, so 2 jobs/wave is safe to retry: j1's compute runs while
// j0's stores drain (no vmcnt waits on stores), staging count halves
// (1024->512 blocks), rounds halve (4->2). WRITE_SIZE is the canary: if it
// balloons ~4x the curse is deeper than partial lines -> revert to R12.
//
// Kept from R12: b-fast grid (bid%8==b%8 pins each XCD's 16 p-passages in
// its L2), block 512 = 8 waves, p[b] staged once to XOR-swizzled LDS, one
// block barrier total, all 24 accs live (pf read once per dt), full-row
// cbuf (11.25KB contiguous per q-half = 180 full 64B lines, 0 partials,
// fill-kernel pattern), in-register maxsim/relevance.
// LDS: plds 46080 + cbuf 8x11520 = 138240 B -> 1 block/CU (8 waves).
__global__ __launch_bounds__(512, 2) void score_kernel(
    const float* __restrict__ q, const float* __restrict__ p,
    float* __restrict__ out) {
  const int bid  = blockIdx.x;
  const int b    = bid & (B_N - 1);
  const int ag   = bid >> 7;          // 0..3
  const int tid  = threadIdx.x;
  const int wv   = tid >> 6;          // 0..7
  const int lane = tid & 63;
  const int l16  = lane & 15;
  const int g    = lane >> 4;         // 0..3

  const float* __restrict__ pb = p + (size_t)b * D_N * V_N;

  // ---- stage p[b] -> LDS bf16, swizzled: 2880 16B-chunks over 512 threads ----
  __shared__ ushort plds[D_N * V_N];                    // 46080 B
  __shared__ __align__(16) float cbuf[8][16 * D_N];     // 8 x 11520 B
  for (int c = tid; c < D_N * (V_N / 8); c += 512) {
    const int r  = c >> 4;
    const int s  = c & 15;
    const int sp = (s & 8) | ((s & 7) ^ (r & 7));
    const float* src = pb + (size_t)r * V_N + s * 8;
    *reinterpret_cast<bf16x8*>(&plds[r * V_N + sp * 8]) =
        pack8(*reinterpret_cast<const f32x4*>(src),
              *reinterpret_cast<const f32x4*>(src + 4));
  }

  // q as B-fragments for BOTH jobs (preloaded; 64 VGPR, free at 1 block/CU):
  // B[k][col=q]; lane reads q[qt*16+l16][kk*32+g*8 ..+7]
  bf16x8 qf[2][2][4];
#pragma unroll
  for (int j = 0; j < 2; ++j) {
    const int a = ag * 16 + j * 8 + wv;
    const float* __restrict__ qa = q + (size_t)a * Q_N * V_N;
#pragma unroll
    for (int qt = 0; qt < 2; ++qt)
#pragma unroll
      for (int kk = 0; kk < 4; ++kk) {
        const float* s = qa + (size_t)(qt * 16 + l16) * V_N + kk * 32 + g * 8;
        qf[j][qt][kk] = pack8(*reinterpret_cast<const f32x4*>(s),
                              *reinterpret_cast<const f32x4*>(s + 4));
      }
  }

  __syncthreads();   // staging complete — the ONLY block barrier

  float* cw = cbuf[wv];
  const size_t TERM_SZ = (size_t)A_N * B_N * Q_N * D_N;
  const size_t MS_SZ   = (size_t)A_N * B_N * Q_N;

#pragma unroll
  for (int j = 0; j < 2; ++j) {   // fully unrolled: all indices compile-time
    const int a = ag * 16 + j * 8 + wv;

    // ---- compute: all 12 d-tiles, both q-halves; pf read once per dt ----
    f32x4 acc[2][12];
#pragma unroll
    for (int qt = 0; qt < 2; ++qt)
#pragma unroll
      for (int dt = 0; dt < 12; ++dt)
        acc[qt][dt] = (f32x4){0.f, 0.f, 0.f, 0.f};

#pragma unroll
    for (int dt = 0; dt < 12; ++dt) {
      const int drow = dt * 16 + l16;
      const int dr   = drow < D_N ? drow : (D_N - 1);  // tail clamp, max-safe

      bf16x8 pf[4];
#pragma unroll
      for (int kk = 0; kk < 4; ++kk) {
        const int s  = kk * 4 + g;
        const int sp = (s & 8) | ((s & 7) ^ (dr & 7));
        pf[kk] = *reinterpret_cast<const bf16x8*>(&plds[dr * V_N + sp * 8]);
      }
#pragma unroll
      for (int kk = 0; kk < 4; ++kk) {
        acc[0][dt] = __builtin_amdgcn_mfma_f32_16x16x32_bf16(pf[kk], qf[j][0][kk], acc[0][dt], 0, 0, 0);
        acc[1][dt] = __builtin_amdgcn_mfma_f32_16x16x32_bf16(pf[kk], qf[j][1][kk], acc[1][dt], 0, 0, 0);
      }
    }

    // per-lane maxsim over owned d (clamped dups are max-safe)
    float qm[2] = {-INFINITY, -INFINITY};
#pragma unroll
    for (int qt = 0; qt < 2; ++qt)
#pragma unroll
      for (int dt = 0; dt < 12; ++dt)
        qm[qt] = fmaxf(qm[qt], fmaxf(fmaxf(acc[qt][dt][0], acc[qt][dt][1]),
                                     fmaxf(acc[qt][dt][2], acc[qt][dt][3])));

    // ---- store: per q-half, assemble 16 full 720B rows in cbuf, stream
    // linearly (11.25KB contiguous, 64B-aligned = 180 full lines) ----
    const size_t outb = ((size_t)a * B_N + b) * (size_t)(Q_N * D_N);
#pragma unroll
    for (int qt = 0; qt < 2; ++qt) {
#pragma unroll
      for (int dt = 0; dt < 12; ++dt) {
        if (dt < 11 || g == 0)   // dt==11: only d 176..179 (g==0) valid
          *reinterpret_cast<f32x4*>(&cw[l16 * D_N + dt * 16 + g * 4]) = acc[qt][dt];
      }
      lds_fence();   // cross-lane: row writes visible before linear reads

#pragma unroll
      for (int c = 0; c < 12; ++c) {       // 11 x 1KB + 1 x 256B (lanes<16)
        const int off = c * 256 + lane * 4;
        if (c < 11 || lane < 16) {
          f32x4 v = *reinterpret_cast<const f32x4*>(&cw[off]);
          *reinterpret_cast<f32x4*>(out + outb + (size_t)qt * 16 * D_N + off) = v;
        }
      }
      lds_fence();   // WAR: reads landed before cbuf is rewritten
    }

    // max across the 4 g-groups (different d sub-rows, same q)
    float qm0 = qm[0], qm1 = qm[1];
    qm0 = fmaxf(qm0, __shfl_xor(qm0, 16, 64));
    qm0 = fmaxf(qm0, __shfl_xor(qm0, 32, 64));
    qm1 = fmaxf(qm1, __shfl_xor(qm1, 16, 64));
    qm1 = fmaxf(qm1, __shfl_xor(qm1, 32, 64));

    if (lane < 16) {   // maxsim for q = qt*16 + lane
      float* ms = out + TERM_SZ + ((size_t)a * B_N + b) * Q_N;
      ms[lane]      = qm0;
      ms[16 + lane] = qm1;
    }

    // relevance = sum over 32 q of maxsim (qm replicated across g-groups)
    float s = qm0 + qm1;
    s += __shfl_xor(s, 1, 64);
    s += __shfl_xor(s, 2, 64);
    s += __shfl_xor(s, 4, 64);
    s += __shfl_xor(s, 8, 64);
    if (lane == 0)
      out[TERM_SZ + MS_SZ + (size_t)a * B_N + b] = s;
  }
}

extern "C" void kernel_launch(void* const* d_in, const int* in_sizes, int n_in,
                              void* d_out, int out_size, void* d_ws, size_t ws_size,
                              hipStream_t stream) {
  const float* q = (const float*)d_in[0];
  const float* p = (const float*)d_in[1];
  float* out = (float*)d_out;
  dim3 grid(512);    // 4 a-groups x 128 b (b fast -> XCD-stable p residency)
  dim3 block(512);   // 8 waves; 2 pipelined (a,b) jobs per wave
  hipLaunchKernelGGL(score_kernel, grid, block, 0, stream, q, p, out);
}

// Round 14
// 42.968 us; speedup vs baseline: 8.0349x; 1.2500x over previous
//
#include <hip/hip_runtime.h>
#include <hip/hip_bf16.h>

// RetrieverBase: q[64][32][128] f32, p[128][180][128] f32
// out = concat(term_relevance[64][128][32][180], query_maxsim[64][128][32], relevance[64][128])
#define A_N 64
#define B_N 128
#define Q_N 32
#define D_N 180
#define V_N 128

typedef __attribute__((ext_vector_type(8))) short bf16x8;   // 8 bf16 (4 VGPRs)
typedef __attribute__((ext_vector_type(4))) float f32x4;

__device__ __forceinline__ short f2bf(float f) {
  __hip_bfloat16 h = __float2bfloat16(f);
  return (short)__builtin_bit_cast(unsigned short, h);
}

__device__ __forceinline__ bf16x8 pack8(const f32x4& lo, const f32x4& hi) {
  bf16x8 v;
  v[0] = f2bf(lo[0]); v[1] = f2bf(lo[1]); v[2] = f2bf(lo[2]); v[3] = f2bf(lo[3]);
  v[4] = f2bf(hi[0]); v[5] = f2bf(hi[1]); v[6] = f2bf(hi[2]); v[7] = f2bf(hi[3]);
  return v;
}

// Per-wave LDS fence (R11-R13 proven): drains this wave's DS queue for the
// cross-lane ds_write -> ds_read handoff. lgkm-only: global stores keep
// draining in the background. NOT a block barrier.
__device__ __forceinline__ void lds_fence() {
  asm volatile("s_waitcnt lgkmcnt(0)" ::: "memory");
  __builtin_amdgcn_sched_barrier(0);
}

// R13 (53.7us) -> ONE round, 4 jobs/wave. Per-CU budget said R13's remaining
// slack was the twice-paid stage(3.4us)+ramp(3us) prologue. grid 256 =
// 2 ag x 128 b (b fast: bid%8==b%8 pins each XCD's 16 p-passages in L2) =
// exactly 1 block/CU: p staged ONCE, ramp paid once, 4 back-to-back jobs
// keep the store pipe continuously fed (fill kernel proves 6.9 TB/s at only
// ~3 waves/CU, so 8 waves suffice if issue never pauses).
// q-fragments double-buffered: job j+1's 8 global loads issue during job j's
// store phase (hides ~300cy). R4/R9 partial-line write-amp is impossible by
// construction (full-line cbuf stores) -- verified safe in R13.
// Kept: block 512 = 8 waves, one job per wave per step, XOR-swizzled plds,
// ONE block barrier, all 24 accs live, full-row cbuf (11.25KB contiguous
// per q-half = 180 full 64B lines), in-register maxsim/relevance.
// LDS: plds 46080 + cbuf 8x11520 = 138240 B -> 1 block/CU.
__global__ __launch_bounds__(512, 2) void score_kernel(
    const float* __restrict__ q, const float* __restrict__ p,
    float* __restrict__ out) {
  const int bid  = blockIdx.x;
  const int b    = bid & (B_N - 1);
  const int ag   = bid >> 7;          // 0..1
  const int tid  = threadIdx.x;
  const int wv   = tid >> 6;          // 0..7
  const int lane = tid & 63;
  const int l16  = lane & 15;
  const int g    = lane >> 4;         // 0..3

  const float* __restrict__ pb = p + (size_t)b * D_N * V_N;

  // ---- stage p[b] -> LDS bf16, swizzled: 2880 16B-chunks over 512 threads ----
  __shared__ ushort plds[D_N * V_N];                    // 46080 B
  __shared__ __align__(16) float cbuf[8][16 * D_N];     // 8 x 11520 B
  for (int c = tid; c < D_N * (V_N / 8); c += 512) {
    const int r  = c >> 4;
    const int s  = c & 15;
    const int sp = (s & 8) | ((s & 7) ^ (r & 7));
    const float* src = pb + (size_t)r * V_N + s * 8;
    *reinterpret_cast<bf16x8*>(&plds[r * V_N + sp * 8]) =
        pack8(*reinterpret_cast<const f32x4*>(src),
              *reinterpret_cast<const f32x4*>(src + 4));
  }

  // q B-fragments, double-buffered across jobs: load job 0 now.
  // B[k][col=q]; lane reads q[qt*16+l16][kk*32+g*8 ..+7]
  bf16x8 qf[2][2][4];   // [buf][qt][kk]
#define LOADQF(buf, jj)                                                       \
  {                                                                           \
    const int aq = ag * 32 + (jj) * 8 + wv;                                   \
    const float* __restrict__ qa = q + (size_t)aq * Q_N * V_N;                \
    _Pragma("unroll")                                                         \
    for (int qt = 0; qt < 2; ++qt)                                            \
      _Pragma("unroll")                                                       \
      for (int kk = 0; kk < 4; ++kk) {                                        \
        const float* s = qa + (size_t)(qt * 16 + l16) * V_N + kk * 32 + g * 8;\
        qf[buf][qt][kk] = pack8(*reinterpret_cast<const f32x4*>(s),          \
                                *reinterpret_cast<const f32x4*>(s + 4));     \
      }                                                                       \
  }
  LOADQF(0, 0);

  __syncthreads();   // staging complete — the ONLY block barrier

  float* cw = cbuf[wv];
  const size_t TERM_SZ = (size_t)A_N * B_N * Q_N * D_N;
  const size_t MS_SZ   = (size_t)A_N * B_N * Q_N;

#pragma unroll
  for (int j = 0; j < 4; ++j) {   // fully unrolled: all indices compile-time
    const int a  = ag * 32 + j * 8 + wv;
    const int jb = j & 1;         // qf buffer for this job (compile-time)

    // ---- compute: all 12 d-tiles, both q-halves; pf read once per dt ----
    f32x4 acc[2][12];
#pragma unroll
    for (int qt = 0; qt < 2; ++qt)
#pragma unroll
      for (int dt = 0; dt < 12; ++dt)
        acc[qt][dt] = (f32x4){0.f, 0.f, 0.f, 0.f};

#pragma unroll
    for (int dt = 0; dt < 12; ++dt) {
      const int drow = dt * 16 + l16;
      const int dr   = drow < D_N ? drow : (D_N - 1);  // tail clamp, max-safe

      bf16x8 pf[4];
#pragma unroll
      for (int kk = 0; kk < 4; ++kk) {
        const int s  = kk * 4 + g;
        const int sp = (s & 8) | ((s & 7) ^ (dr & 7));
        pf[kk] = *reinterpret_cast<const bf16x8*>(&plds[dr * V_N + sp * 8]);
      }
#pragma unroll
      for (int kk = 0; kk < 4; ++kk) {
        acc[0][dt] = __builtin_amdgcn_mfma_f32_16x16x32_bf16(pf[kk], qf[jb][0][kk], acc[0][dt], 0, 0, 0);
        acc[1][dt] = __builtin_amdgcn_mfma_f32_16x16x32_bf16(pf[kk], qf[jb][1][kk], acc[1][dt], 0, 0, 0);
      }
    }

    // prefetch next job's q-fragments: global loads issue here and complete
    // under this job's store phase (compiler inserts the waitcnt at next use)
    if (j < 3) LOADQF(!jb ? 1 : 0, j + 1);

    // per-lane maxsim over owned d (clamped dups are max-safe)
    float qm[2] = {-INFINITY, -INFINITY};
#pragma unroll
    for (int qt = 0; qt < 2; ++qt)
#pragma unroll
      for (int dt = 0; dt < 12; ++dt)
        qm[qt] = fmaxf(qm[qt], fmaxf(fmaxf(acc[qt][dt][0], acc[qt][dt][1]),
                                     fmaxf(acc[qt][dt][2], acc[qt][dt][3])));

    // ---- store: per q-half, assemble 16 full 720B rows in cbuf, stream
    // linearly (11.25KB contiguous, 64B-aligned = 180 full lines) ----
    const size_t outb = ((size_t)a * B_N + b) * (size_t)(Q_N * D_N);
#pragma unroll
    for (int qt = 0; qt < 2; ++qt) {
#pragma unroll
      for (int dt = 0; dt < 12; ++dt) {
        if (dt < 11 || g == 0)   // dt==11: only d 176..179 (g==0) valid
          *reinterpret_cast<f32x4*>(&cw[l16 * D_N + dt * 16 + g * 4]) = acc[qt][dt];
      }
      lds_fence();   // cross-lane: row writes visible before linear reads

#pragma unroll
      for (int c = 0; c < 12; ++c) {       // 11 x 1KB + 1 x 256B (lanes<16)
        const int off = c * 256 + lane * 4;
        if (c < 11 || lane < 16) {
          f32x4 v = *reinterpret_cast<const f32x4*>(&cw[off]);
          *reinterpret_cast<f32x4*>(out + outb + (size_t)qt * 16 * D_N + off) = v;
        }
      }
      lds_fence();   // WAR: reads landed before cbuf is rewritten
    }

    // max across the 4 g-groups (different d sub-rows, same q)
    float qm0 = qm[0], qm1 = qm[1];
    qm0 = fmaxf(qm0, __shfl_xor(qm0, 16, 64));
    qm0 = fmaxf(qm0, __shfl_xor(qm0, 32, 64));
    qm1 = fmaxf(qm1, __shfl_xor(qm1, 16, 64));
    qm1 = fmaxf(qm1, __shfl_xor(qm1, 32, 64));

    if (lane < 16) {   // maxsim for q = qt*16 + lane
      float* ms = out + TERM_SZ + ((size_t)a * B_N + b) * Q_N;
      ms[lane]      = qm0;
      ms[16 + lane] = qm1;
    }

    // relevance = sum over 32 q of maxsim (qm replicated across g-groups)
    float s = qm0 + qm1;
    s += __shfl_xor(s, 1, 64);
    s += __shfl_xor(s, 2, 64);
    s += __shfl_xor(s, 4, 64);
    s += __shfl_xor(s, 8, 64);
    if (lane == 0)
      out[TERM_SZ + MS_SZ + (size_t)a * B_N + b] = s;
  }
#undef LOADQF
}

extern "C" void kernel_launch(void* const* d_in, const int* in_sizes, int n_in,
                              void* d_out, int out_size, void* d_ws, size_t ws_size,
                              hipStream_t stream) {
  const float* q = (const float*)d_in[0];
  const float* p = (const float*)d_in[1];
  float* out = (float*)d_out;
  dim3 grid(256);    // 2 a-groups x 128 b: exactly one block per CU
  dim3 block(512);   // 8 waves; 4 pipelined (a,b) jobs per wave
  hipLaunchKernelGGL(score_kernel, grid, block, 0, stream, q, p, out);
}